// Round 7
// baseline (669.105 us; speedup 1.0000x reference)
//
#include <hip/hip_runtime.h>
#include <hip/hip_cooperative_groups.h>
#include <math.h>

namespace cg = cooperative_groups;

// Problem constants
#define Bsz   16
#define Lseq  512
#define Nfeat 32
#define E     128
#define EMB   8
#define FCH   64
#define Hd    256
#define PRE   96
#define M     16384   // N*L
#define MH    8193
#define LAMBDA 0.01f

// workspace layout (float offsets)
#define OFF_G   0          // 16*128*128*2 = 524288 floats
#define OFF_CS  524288     // 8193*16 -> 131088 floats
#define OFF_P   655376     // 128*16*1024 = 2097152 floats
// total = 2752528 floats = 11.01 MB

#define REV_M   6.103515625e-5f    // 1/16384 (angle in revolutions)
#define REV_128 7.8125e-3f         // 1/128

#define SBUF_N  4160               // 16.64 KB shared, aliased per stage

__device__ __forceinline__ float sin_rev(float r) { return __builtin_amdgcn_sinf(r); }
__device__ __forceinline__ float cos_rev(float r) { return __builtin_amdgcn_cosf(r); }

// ---------------- stage 0: FFT pass1 + C/S tables ----------------
__device__ __forceinline__ void stage_prep(int bid, int tid,
    const float* __restrict__ x, const float* __restrict__ emb10,
    float* __restrict__ ws, float* sbuf) {
  // ----- FFT pass 1: G'[b,f1,t1], unit = bid (16 b x 64 t1-pairs)
  {
    int b = bid >> 6, t1base = (bid & 63) << 1;
    int t1loc = tid >> 7, idx = tid & 127;
    {
      int t = (t1base + t1loc) + 128 * idx;
      int n = t >> 9, l = t & 511;
      sbuf[t1loc * 128 + idx] = x[b * (Lseq * Nfeat) + l * Nfeat + n];
    }
    __syncthreads();
    int f1 = idx, t1 = t1base + t1loc;
    float s1 = sin_rev((float)f1 * REV_128), c1 = cos_rev((float)f1 * REV_128);
    float c2 = c1 * c1 - s1 * s1, s2 = 2.f * s1 * c1;
    float cA = 1.f, sA = 0.f, cB = c1, sB = s1;
    float grA = 0.f, giA = 0.f, grB = 0.f, giB = 0.f;
    const float2* xc2 = (const float2*)(sbuf + t1loc * 128);
    #pragma unroll 8
    for (int h = 0; h < 64; ++h) {
      float2 xv = xc2[h];
      grA = fmaf(xv.x, cA, grA); giA = fmaf(xv.x, -sA, giA);
      grB = fmaf(xv.y, cB, grB); giB = fmaf(xv.y, -sB, giB);
      float cn = cA * c2 - sA * s2; sA = sA * c2 + cA * s2; cA = cn;
      cn = cB * c2 - sB * s2;       sB = sB * c2 + cB * s2; cB = cn;
    }
    float gr = grA + grB, gi = giA + giB;
    float rv = (float)(f1 * t1) * REV_M;            // f1*t1 < 16384
    float sb = sin_rev(rv), cb = cos_rev(rv);
    float grr = gr * cb + gi * sb;
    float gii = gi * cb - gr * sb;
    float* G = ws + OFF_G + ((b * 128 + f1) * 128 + t1) * 2;
    G[0] = grr; G[1] = gii;
  }
  __syncthreads();
  // ----- C/S tables: f = bid*8 + (tid>>5), covers 0..8191; block 0 adds 8192
  {
    for (int i = tid; i < Lseq * EMB; i += 256) sbuf[i] = emb10[i];
    __syncthreads();
    int floc = tid >> 5, tl = tid & 31;
    int f = bid * 8 + floc;
    float ca[EMB], sa[EMB];
    #pragma unroll
    for (int m = 0; m < EMB; ++m) { ca[m] = 0.f; sa[m] = 0.f; }
    #pragma unroll 4
    for (int it = 0; it < 16; ++it) {
      int t = tl + 32 * it;
      int k = (f * t) & (M - 1);
      float rv = (float)k * REV_M;
      float cc = cos_rev(rv), ss = sin_rev(rv);
      const float2* er = (const float2*)(sbuf + t * EMB);
      float2 e01 = er[0], e23 = er[1], e45 = er[2], e67 = er[3];
      ca[0] = fmaf(cc, e01.x, ca[0]); sa[0] = fmaf(ss, e01.x, sa[0]);
      ca[1] = fmaf(cc, e01.y, ca[1]); sa[1] = fmaf(ss, e01.y, sa[1]);
      ca[2] = fmaf(cc, e23.x, ca[2]); sa[2] = fmaf(ss, e23.x, sa[2]);
      ca[3] = fmaf(cc, e23.y, ca[3]); sa[3] = fmaf(ss, e23.y, sa[3]);
      ca[4] = fmaf(cc, e45.x, ca[4]); sa[4] = fmaf(ss, e45.x, sa[4]);
      ca[5] = fmaf(cc, e45.y, ca[5]); sa[5] = fmaf(ss, e45.y, sa[5]);
      ca[6] = fmaf(cc, e67.x, ca[6]); sa[6] = fmaf(ss, e67.x, sa[6]);
      ca[7] = fmaf(cc, e67.y, ca[7]); sa[7] = fmaf(ss, e67.y, sa[7]);
    }
    #pragma unroll
    for (int off = 16; off >= 1; off >>= 1) {
      #pragma unroll
      for (int m = 0; m < EMB; ++m) {
        ca[m] += __shfl_xor(ca[m], off, 64);
        sa[m] += __shfl_xor(sa[m], off, 64);
      }
    }
    if (tl == 0) {
      float wf = (f == 0) ? (1.0f / 128.0f) : (2.0f / 128.0f);
      float* o = ws + OFF_CS + f * 16;
      #pragma unroll
      for (int m = 0; m < EMB; ++m) { o[m] = ca[m] * wf; o[8 + m] = sa[m] * wf; }
    }
    if (bid == 0 && tid < 64) {          // f = 8192: cos = (-1)^t, sin = 0
      int m = tid & 7, g = tid >> 3;
      float p = 0.f;
      #pragma unroll 8
      for (int j = 0; j < 64; ++j) p += sbuf[(g + 8 * j) * EMB + m];
      p = (g & 1) ? -p : p;
      p += __shfl_xor(p, 8, 64);
      p += __shfl_xor(p, 16, 64);
      p += __shfl_xor(p, 32, 64);
      if (g == 0) {
        ws[OFF_CS + 8192 * 16 + m] = p * (1.0f / 128.0f);
        ws[OFF_CS + 8192 * 16 + 8 + m] = 0.f;
      }
    }
  }
}

// ---------------- stage 1: FFT pass2 + fourierGC + partial reduce ----------------
__device__ __forceinline__ void stage_gcf(int u, int tid,
    const float* __restrict__ emb,
    const float* __restrict__ w0, const float* __restrict__ b0,
    const float* __restrict__ w1, const float* __restrict__ b1,
    const float* __restrict__ w2, const float* __restrict__ b2,
    float* __restrict__ ws, float* sbuf) {
  int f1 = u >> 4, b = u & 15;
  int nf2 = (f1 == 0) ? 65 : 64;
  float2* Gs = (float2*)sbuf;            // stride-33 quarters, 132 float2
  float2* Xs = (float2*)(sbuf + 272);    // 65 float2
  float* red = sbuf + 512;               // 1024 floats
  __syncthreads();                       // protect prior smem contents
  if (tid < 128)
    Gs[(tid >> 5) * 33 + (tid & 31)] =
        ((const float2*)(ws + OFF_G + (b * 128 + f1) * 256))[tid];
  __syncthreads();
  // phase A: X[f1+128 f2] = sum_t1 G'[t1] W128^{f2 t1} (quarters + shfl)
  {
    int lane = tid & 63, w = tid >> 6;
    int q = lane >> 4, f2l = lane & 15;
    int f2 = w * 16 + f2l;
    int r = (f2 * q) & 3;                // start angle f2*q/4 rev: exact
    float c = (r == 0) ? 1.f : (r == 2) ? -1.f : 0.f;
    float s = (r == 1) ? 1.f : (r == 3) ? -1.f : 0.f;
    float s1 = sin_rev((float)f2 * REV_128), c1 = cos_rev((float)f2 * REV_128);
    float xr = 0.f, xi = 0.f;
    const float2* g = Gs + q * 33;
    #pragma unroll 8
    for (int k = 0; k < 32; ++k) {
      float2 gv = g[k];
      xr = fmaf(gv.x, c, xr); xr = fmaf(gv.y, s, xr);
      xi = fmaf(gv.y, c, xi); xi = fmaf(-gv.x, s, xi);
      float cn = c * c1 - s * s1; s = s * c1 + c * s1; c = cn;
    }
    xr += __shfl_xor(xr, 16, 64); xi += __shfl_xor(xi, 16, 64);
    xr += __shfl_xor(xr, 32, 64); xi += __shfl_xor(xi, 32, 64);
    if (lane < 16) Xs[f2] = make_float2(xr, xi);
    if (f1 == 0 && tid < 32) {           // f2=64 (f=8192): W = (-1)^t1
      float er = 0.f, ei = 0.f;
      #pragma unroll
      for (int j = 0; j < 4; ++j) {
        int t1v = tid * 4 + j;
        float2 gv = Gs[(t1v >> 5) * 33 + (t1v & 31)];
        float sg = (j & 1) ? -1.f : 1.f;
        er = fmaf(gv.x, sg, er); ei = fmaf(gv.y, sg, ei);
      }
      #pragma unroll
      for (int off = 1; off <= 16; off <<= 1) {
        er += __shfl_xor(er, off, 64);
        ei += __shfl_xor(ei, off, 64);
      }
      if (tid == 0) Xs[64] = make_float2(er, ei);
    }
  }
  __syncthreads();
  // phase B: GC chain + CS-weighted reduction
  int e = tid & 127, fh = tid >> 7;
  float se  = emb[e] * (1.0f / 128.0f);  // ortho forward scale
  float d00 = w0[e * 129], d01 = w0[E * E + e * 129];
  float c00 = b0[e],       c01 = b0[E + e];
  float d10 = w1[e * 129], d11 = w1[E * E + e * 129];
  float c10 = b1[e],       c11 = b1[E + e];
  float d20 = w2[e * 129], d21 = w2[E * E + e * 129];
  float c20 = b2[e],       c21 = b2[E + e];
  float acc[EMB];
  #pragma unroll
  for (int m = 0; m < EMB; ++m) acc[m] = 0.f;
  const float* csbase = ws + OFF_CS + f1 * 16;

  for (int i = fh; i < nf2; i += 2) {
    int iu = __builtin_amdgcn_readfirstlane(i);
    const float* cs = csbase + (iu << 11);           // (f1 + 128*i)*16
    float2 X = Xs[i];
    float xr = X.x * se, xi = X.y * se;
    float or0 = fmaxf(fmaf(xr, d00, fmaf(-xi, d01, c00)), 0.f);
    float oi0 = fmaxf(fmaf(xi, d00, fmaf(xr, d01, c01)), 0.f);
    float pr = fmaxf(or0 - LAMBDA, 0.f), pi = fmaxf(oi0 - LAMBDA, 0.f);
    float or1 = fmaxf(fmaf(or0, d10, fmaf(-oi0, d11, c10)), 0.f);
    float oi1 = fmaxf(fmaf(oi0, d10, fmaf(or1, d11, c11)), 0.f);
    pr += fmaxf(or1 - LAMBDA, 0.f); pi += fmaxf(oi1 - LAMBDA, 0.f);
    float u2r = fmaf(or1, d20, fmaf(-oi1, d21, c20));
    float or2 = fmaxf(u2r, 0.f);
    float u2i = fmaf(oi1, d20, fmaf(or2, d21, c21));
    float zr = fmaxf(u2r - LAMBDA, 0.f) + pr;        // shrink(relu(u)) = max(u-l,0)
    float zi = fmaxf(u2i - LAMBDA, 0.f) + pi;
    #pragma unroll
    for (int m = 0; m < EMB; ++m)
      acc[m] = fmaf(zr, cs[m], fmaf(-zi, cs[8 + m], acc[m]));
  }
  __syncthreads();
  if (fh == 1) {
    #pragma unroll
    for (int m = 0; m < EMB; ++m) red[e * EMB + m] = acc[m];
  }
  __syncthreads();
  if (fh == 0) {
    float* P = ws + OFF_P + u * (E * EMB) + e * EMB;
    #pragma unroll
    for (int m = 0; m < EMB; ++m) P[m] = acc[m] + red[e * EMB + m];
  }
}

// ---------------- stage 2: P-reduce + bias skip + FC head ----------------
__device__ __forceinline__ void stage_fc(int b, int tid,
    const float* __restrict__ x, const float* __restrict__ emb,
    const float* __restrict__ emb10,
    const float* __restrict__ fc1w, const float* __restrict__ fc1b,
    const float* __restrict__ fc2w, const float* __restrict__ fc2b,
    const float* __restrict__ fc3w, const float* __restrict__ fc3b,
    const float* __restrict__ ws, float* __restrict__ out, float* sbuf) {
  float* h0s = sbuf;                    // 1024
  float* h1s = sbuf + 1024;             // 64
  float* h2s = sbuf + 1088;             // 256
  float* hxs = sbuf + 1344;             // 8
  float* hxp = sbuf + 1352;             // 32
  int lane = tid & 63, w = tid >> 6;    // 4 waves
  __syncthreads();
  {
    int m = lane & 7, g8 = lane >> 3;
    int gg = w * 8 + g8;                // 32 l-groups
    float p = 0.f;
    #pragma unroll
    for (int l = gg; l < Lseq; l += 32)
      p = fmaf(x[b * (Lseq * Nfeat) + l * Nfeat], emb10[l * EMB + m], p);
    p += __shfl_xor(p, 8, 64);
    p += __shfl_xor(p, 16, 64);
    p += __shfl_xor(p, 32, 64);
    if (lane < 8) hxp[w * 8 + lane] = p;
  }
  __syncthreads();
  if (tid < 8) hxs[tid] = hxp[tid] + hxp[8 + tid] + hxp[16 + tid] + hxp[24 + tid];
  // P-reduce: thread owns k = tid + 256*j
  const float* P = ws + OFF_P + b * (E * EMB) + tid;
  float a0 = 0.f, a1 = 0.f, a2 = 0.f, a3 = 0.f;
  #pragma unroll 8
  for (int c = 0; c < 128; ++c) {
    const float* p = P + c * (Bsz * E * EMB);
    a0 += p[0]; a1 += p[256]; a2 += p[512]; a3 += p[768];
  }
  __syncthreads();
  float hm = hxs[tid & 7];
  h0s[tid]       = a0 + emb[tid >> 3] * hm;
  h0s[tid + 256] = a1 + emb[(tid + 256) >> 3] * hm;
  h0s[tid + 512] = a2 + emb[(tid + 512) >> 3] * hm;
  h0s[tid + 768] = a3 + emb[(tid + 768) >> 3] * hm;
  __syncthreads();
  // fc1: 64 outputs, K=1024, wave-per-output
  #pragma unroll
  for (int oo = 0; oo < 16; ++oo) {
    int o = oo * 4 + w;
    const float* wr = fc1w + o * (E * EMB);
    float a = 0.f;
    #pragma unroll
    for (int j = 0; j < 16; ++j) a = fmaf(h0s[lane + 64 * j], wr[lane + 64 * j], a);
    #pragma unroll
    for (int off = 32; off >= 1; off >>= 1) a += __shfl_xor(a, off, 64);
    if (lane == 0) { float v = a + fc1b[o]; h1s[o] = v > 0.f ? v : 0.01f * v; }
  }
  __syncthreads();
  // fc2: 256 outputs, K=64
  #pragma unroll 8
  for (int oo = 0; oo < 64; ++oo) {
    int o = oo * 4 + w;
    float a = h1s[lane] * fc2w[o * FCH + lane];
    #pragma unroll
    for (int off = 32; off >= 1; off >>= 1) a += __shfl_xor(a, off, 64);
    if (lane == 0) { float v = a + fc2b[o]; h2s[o] = v > 0.f ? v : 0.01f * v; }
  }
  __syncthreads();
  // fc3: 96 outputs, K=256
  #pragma unroll
  for (int oo = 0; oo < 24; ++oo) {
    int o = oo * 4 + w;
    const float* wr = fc3w + o * Hd;
    float a = 0.f;
    #pragma unroll
    for (int j = 0; j < 4; ++j) a = fmaf(h2s[lane + 64 * j], wr[lane + 64 * j], a);
    #pragma unroll
    for (int off = 32; off >= 1; off >>= 1) a += __shfl_xor(a, off, 64);
    if (lane == 0) out[b * PRE + o] = a + fc3b[o];
  }
}

// ---------------- cooperative all-in-one ----------------
__global__ __launch_bounds__(256, 4)
void k_all(const float* __restrict__ x, const float* __restrict__ emb,
           const float* __restrict__ w0, const float* __restrict__ b0,
           const float* __restrict__ w1, const float* __restrict__ b1,
           const float* __restrict__ w2, const float* __restrict__ b2,
           const float* __restrict__ emb10,
           const float* __restrict__ fc1w, const float* __restrict__ fc1b,
           const float* __restrict__ fc2w, const float* __restrict__ fc2b,
           const float* __restrict__ fc3w, const float* __restrict__ fc3b,
           float* __restrict__ ws, float* __restrict__ out) {
  __shared__ __align__(16) float sbuf[SBUF_N];
  cg::grid_group grid = cg::this_grid();
  int bid = blockIdx.x, tid = threadIdx.x;
  stage_prep(bid, tid, x, emb10, ws, sbuf);
  __threadfence();
  grid.sync();
  stage_gcf(bid, tid, emb, w0, b0, w1, b1, w2, b2, ws, sbuf);
  stage_gcf(bid + 1024, tid, emb, w0, b0, w1, b1, w2, b2, ws, sbuf);
  __threadfence();
  grid.sync();
  if (bid < Bsz)
    stage_fc(bid, tid, x, emb, emb10, fc1w, fc1b, fc2w, fc2b, fc3w, fc3b, ws, out, sbuf);
}

// ---------------- fallback: 3 plain kernels ----------------
__global__ __launch_bounds__(256)
void k_prep_g(const float* __restrict__ x, const float* __restrict__ emb10,
              float* __restrict__ ws) {
  __shared__ __align__(16) float sbuf[SBUF_N];
  stage_prep(blockIdx.x, threadIdx.x, x, emb10, ws, sbuf);
}
__global__ __launch_bounds__(256)
void k_gcf_g(const float* __restrict__ emb,
             const float* __restrict__ w0, const float* __restrict__ b0,
             const float* __restrict__ w1, const float* __restrict__ b1,
             const float* __restrict__ w2, const float* __restrict__ b2,
             float* __restrict__ ws) {
  __shared__ __align__(16) float sbuf[SBUF_N];
  stage_gcf(blockIdx.x, threadIdx.x, emb, w0, b0, w1, b1, w2, b2, ws, sbuf);
}
__global__ __launch_bounds__(256)
void k_fc_g(const float* __restrict__ x, const float* __restrict__ emb,
            const float* __restrict__ emb10,
            const float* __restrict__ fc1w, const float* __restrict__ fc1b,
            const float* __restrict__ fc2w, const float* __restrict__ fc2b,
            const float* __restrict__ fc3w, const float* __restrict__ fc3b,
            const float* __restrict__ ws, float* __restrict__ out) {
  __shared__ __align__(16) float sbuf[SBUF_N];
  stage_fc(blockIdx.x, threadIdx.x, x, emb, emb10, fc1w, fc1b, fc2w, fc2b,
           fc3w, fc3b, ws, out, sbuf);
}

extern "C" void kernel_launch(void* const* d_in, const int* in_sizes, int n_in,
                              void* d_out, int out_size, void* d_ws, size_t ws_size,
                              hipStream_t stream) {
  const float* x     = (const float*)d_in[0];
  const float* emb   = (const float*)d_in[1];
  const float* w0    = (const float*)d_in[2];
  const float* b0    = (const float*)d_in[3];
  const float* w1    = (const float*)d_in[4];
  const float* b1    = (const float*)d_in[5];
  const float* w2    = (const float*)d_in[6];
  const float* b2    = (const float*)d_in[7];
  const float* emb10 = (const float*)d_in[8];
  const float* fc1w  = (const float*)d_in[9];
  const float* fc1b  = (const float*)d_in[10];
  const float* fc2w  = (const float*)d_in[11];
  const float* fc2b  = (const float*)d_in[12];
  const float* fc3w  = (const float*)d_in[13];
  const float* fc3b  = (const float*)d_in[14];
  float* ws  = (float*)d_ws;
  float* out = (float*)d_out;

  int coop = 0, dev = 0;
  hipGetDevice(&dev);
  hipDeviceGetAttribute(&coop, hipDeviceAttributeCooperativeLaunch, dev);
  if (coop) {
    void* args[] = {(void*)&x, (void*)&emb, (void*)&w0, (void*)&b0,
                    (void*)&w1, (void*)&b1, (void*)&w2, (void*)&b2,
                    (void*)&emb10, (void*)&fc1w, (void*)&fc1b,
                    (void*)&fc2w, (void*)&fc2b, (void*)&fc3w, (void*)&fc3b,
                    (void*)&ws, (void*)&out};
    hipError_t e = hipLaunchCooperativeKernel((const void*)k_all, dim3(1024),
                                              dim3(256), args, 0, stream);
    if (e == hipSuccess) return;
  }
  k_prep_g<<<dim3(1024), 256, 0, stream>>>(x, emb10, ws);
  k_gcf_g<<<dim3(2048), 256, 0, stream>>>(emb, w0, b0, w1, b1, w2, b2, ws);
  k_fc_g<<<dim3(Bsz), 256, 0, stream>>>(x, emb, emb10, fc1w, fc1b, fc2w, fc2b,
                                        fc3w, fc3b, ws, out);
}

// Round 9
// 302.002 us; speedup vs baseline: 2.2156x; 2.2156x over previous
//
#include <hip/hip_runtime.h>
#include <math.h>

// Problem constants
#define Bsz   16
#define Lseq  512
#define Nfeat 32
#define E     128
#define EMB   8
#define FCH   64
#define Hd    256
#define PRE   96
#define M     16384   // N*L
#define MH    8193
#define LAMBDA 0.01f

// workspace layout (float offsets)
#define OFF_G   0          // 16*128*128*2 = 524288 floats
#define OFF_CS  524288     // 8193*16 -> 131088 floats
#define OFF_P   655376     // 128*16*1024 = 2097152 floats
#define OFF_CTR 2752528    // 16 uint counters
// total ~ 2752544 floats = 11.01 MB

#define REV_M   6.103515625e-5f    // 1/16384 (angle in revolutions)
#define REV_128 7.8125e-3f         // 1/128

#define SBUF_N  4160               // 16.64 KB shared, aliased per stage
#define FLAG_SLOT 4096             // outside every stage's region

__device__ __forceinline__ float sin_rev(float r) { return __builtin_amdgcn_sinf(r); }
__device__ __forceinline__ float cos_rev(float r) { return __builtin_amdgcn_cosf(r); }

// ---------------- kernel 1: FFT pass1 + C/S tables ----------------
__global__ __launch_bounds__(256, 4)
void k_prep(const float* __restrict__ x, const float* __restrict__ emb10,
            float* __restrict__ ws) {
  __shared__ __align__(16) float sbuf[SBUF_N];
  int bid = blockIdx.x, tid = threadIdx.x;
  // ----- FFT pass 1: G'[b,f1,t1], unit = bid (16 b x 64 t1-pairs)
  {
    int b = bid >> 6, t1base = (bid & 63) << 1;
    int t1loc = tid >> 7, idx = tid & 127;
    {
      int t = (t1base + t1loc) + 128 * idx;
      int n = t >> 9, l = t & 511;
      sbuf[t1loc * 128 + idx] = x[b * (Lseq * Nfeat) + l * Nfeat + n];
    }
    __syncthreads();
    int f1 = idx, t1 = t1base + t1loc;
    float s1 = sin_rev((float)f1 * REV_128), c1 = cos_rev((float)f1 * REV_128);
    float c2 = c1 * c1 - s1 * s1, s2 = 2.f * s1 * c1;
    float cA = 1.f, sA = 0.f, cB = c1, sB = s1;
    float grA = 0.f, giA = 0.f, grB = 0.f, giB = 0.f;
    const float2* xc2 = (const float2*)(sbuf + t1loc * 128);
    #pragma unroll 8
    for (int h = 0; h < 64; ++h) {
      float2 xv = xc2[h];
      grA = fmaf(xv.x, cA, grA); giA = fmaf(xv.x, -sA, giA);
      grB = fmaf(xv.y, cB, grB); giB = fmaf(xv.y, -sB, giB);
      float cn = cA * c2 - sA * s2; sA = sA * c2 + cA * s2; cA = cn;
      cn = cB * c2 - sB * s2;       sB = sB * c2 + cB * s2; cB = cn;
    }
    float gr = grA + grB, gi = giA + giB;
    float rv = (float)(f1 * t1) * REV_M;            // f1*t1 < 16384
    float sb = sin_rev(rv), cb = cos_rev(rv);
    float grr = gr * cb + gi * sb;
    float gii = gi * cb - gr * sb;
    float* G = ws + OFF_G + ((b * 128 + f1) * 128 + t1) * 2;
    G[0] = grr; G[1] = gii;
  }
  __syncthreads();
  // ----- C/S tables: f = bid*8 + (tid>>5); emb10 staged TRANSPOSED e10T[m][t]
  {
    for (int j = tid; j < Lseq * EMB; j += 256) {
      int t = j >> 3, m = j & 7;
      sbuf[m * 512 + t] = emb10[j];     // coalesced global read
    }
    __syncthreads();
    int floc = tid >> 5, tl = tid & 31;
    int f = bid * 8 + floc;
    float ca[EMB], sa[EMB];
    #pragma unroll
    for (int m = 0; m < EMB; ++m) { ca[m] = 0.f; sa[m] = 0.f; }
    #pragma unroll 4
    for (int it = 0; it < 16; ++it) {
      int t = tl + 32 * it;
      int k = (f * t) & (M - 1);
      float rv = (float)k * REV_M;
      float cc = cos_rev(rv), ss = sin_rev(rv);
      #pragma unroll
      for (int m = 0; m < EMB; ++m) {
        float ev = sbuf[m * 512 + t];   // bank = t%32 = tl -> conflict-free
        ca[m] = fmaf(cc, ev, ca[m]);
        sa[m] = fmaf(ss, ev, sa[m]);
      }
    }
    #pragma unroll
    for (int off = 16; off >= 1; off >>= 1) {
      #pragma unroll
      for (int m = 0; m < EMB; ++m) {
        ca[m] += __shfl_xor(ca[m], off, 64);
        sa[m] += __shfl_xor(sa[m], off, 64);
      }
    }
    if (tl == 0) {
      float wf = (f == 0) ? (1.0f / 128.0f) : (2.0f / 128.0f);
      float* o = ws + OFF_CS + f * 16;
      #pragma unroll
      for (int m = 0; m < EMB; ++m) { o[m] = ca[m] * wf; o[8 + m] = sa[m] * wf; }
    }
    if (bid == 0 && tid < 64) {          // f = 8192: cos = (-1)^t, sin = 0
      int m = tid & 7, g = tid >> 3;
      float p = 0.f;
      #pragma unroll 8
      for (int j = 0; j < 64; ++j) p += sbuf[m * 512 + g + 8 * j];
      p = (g & 1) ? -p : p;
      p += __shfl_xor(p, 8, 64);
      p += __shfl_xor(p, 16, 64);
      p += __shfl_xor(p, 32, 64);
      if (g == 0) {
        ws[OFF_CS + 8192 * 16 + m] = p * (1.0f / 128.0f);
        ws[OFF_CS + 8192 * 16 + 8 + m] = 0.f;
      }
    }
  }
}

// ---------------- FC head for one b (runs in the finisher block) ----------------
__device__ __forceinline__ void stage_fc(int b, int tid,
    const float* __restrict__ x, const float* __restrict__ emb,
    const float* __restrict__ emb10,
    const float* __restrict__ fc1w, const float* __restrict__ fc1b,
    const float* __restrict__ fc2w, const float* __restrict__ fc2b,
    const float* __restrict__ fc3w, const float* __restrict__ fc3b,
    const float* __restrict__ ws, float* __restrict__ out, float* sbuf) {
  float* h0s = sbuf;                    // 1024
  float* h1s = sbuf + 1024;             // 64
  float* h2s = sbuf + 1088;             // 256
  float* hxs = sbuf + 1344;             // 8
  float* hxp = sbuf + 1352;             // 32
  int lane = tid & 63, w = tid >> 6;    // 4 waves
  __syncthreads();
  {
    int m = lane & 7, g8 = lane >> 3;
    int gg = w * 8 + g8;                // 32 l-groups
    float p = 0.f;
    #pragma unroll
    for (int l = gg; l < Lseq; l += 32)
      p = fmaf(x[b * (Lseq * Nfeat) + l * Nfeat], emb10[l * EMB + m], p);
    p += __shfl_xor(p, 8, 64);
    p += __shfl_xor(p, 16, 64);
    p += __shfl_xor(p, 32, 64);
    if (lane < 8) hxp[w * 8 + lane] = p;
  }
  __syncthreads();
  if (tid < 8) hxs[tid] = hxp[tid] + hxp[8 + tid] + hxp[16 + tid] + hxp[24 + tid];
  // P-reduce: thread owns k = tid + 256*j
  const float* P = ws + OFF_P + b * (E * EMB) + tid;
  float a0 = 0.f, a1 = 0.f, a2 = 0.f, a3 = 0.f;
  #pragma unroll 8
  for (int c = 0; c < 128; ++c) {
    const float* p = P + c * (Bsz * E * EMB);
    a0 += p[0]; a1 += p[256]; a2 += p[512]; a3 += p[768];
  }
  __syncthreads();
  float hm = hxs[tid & 7];
  h0s[tid]       = a0 + emb[tid >> 3] * hm;
  h0s[tid + 256] = a1 + emb[(tid + 256) >> 3] * hm;
  h0s[tid + 512] = a2 + emb[(tid + 512) >> 3] * hm;
  h0s[tid + 768] = a3 + emb[(tid + 768) >> 3] * hm;
  __syncthreads();
  // fc1: 64 outputs, K=1024, wave-per-output
  #pragma unroll
  for (int oo = 0; oo < 16; ++oo) {
    int o = oo * 4 + w;
    const float* wr = fc1w + o * (E * EMB);
    float a = 0.f;
    #pragma unroll
    for (int j = 0; j < 16; ++j) a = fmaf(h0s[lane + 64 * j], wr[lane + 64 * j], a);
    #pragma unroll
    for (int off = 32; off >= 1; off >>= 1) a += __shfl_xor(a, off, 64);
    if (lane == 0) { float v = a + fc1b[o]; h1s[o] = v > 0.f ? v : 0.01f * v; }
  }
  __syncthreads();
  // fc2: 256 outputs, K=64
  #pragma unroll 8
  for (int oo = 0; oo < 64; ++oo) {
    int o = oo * 4 + w;
    float a = h1s[lane] * fc2w[o * FCH + lane];
    #pragma unroll
    for (int off = 32; off >= 1; off >>= 1) a += __shfl_xor(a, off, 64);
    if (lane == 0) { float v = a + fc2b[o]; h2s[o] = v > 0.f ? v : 0.01f * v; }
  }
  __syncthreads();
  // fc3: 96 outputs, K=256
  #pragma unroll
  for (int oo = 0; oo < 24; ++oo) {
    int o = oo * 4 + w;
    const float* wr = fc3w + o * Hd;
    float a = 0.f;
    #pragma unroll
    for (int j = 0; j < 4; ++j) a = fmaf(h2s[lane + 64 * j], wr[lane + 64 * j], a);
    #pragma unroll
    for (int off = 32; off >= 1; off >>= 1) a += __shfl_xor(a, off, 64);
    if (lane == 0) out[b * PRE + o] = a + fc3b[o];
  }
}

// ---------------- kernel 2: FFT pass2 + fourierGC + P write + finisher FC ----------------
__global__ __launch_bounds__(256, 4)
void k_gcf(const float* __restrict__ x, const float* __restrict__ emb,
           const float* __restrict__ w0, const float* __restrict__ b0,
           const float* __restrict__ w1, const float* __restrict__ b1,
           const float* __restrict__ w2, const float* __restrict__ b2,
           const float* __restrict__ emb10,
           const float* __restrict__ fc1w, const float* __restrict__ fc1b,
           const float* __restrict__ fc2w, const float* __restrict__ fc2b,
           const float* __restrict__ fc3w, const float* __restrict__ fc3b,
           float* __restrict__ ws, float* __restrict__ out) {
  __shared__ __align__(16) float sbuf[SBUF_N];
  int u = blockIdx.x, tid = threadIdx.x;
  int f1 = u >> 4, b = u & 15;
  int nf2 = (f1 == 0) ? 65 : 64;
  float2* Gs = (float2*)sbuf;            // stride-33 quarters, 132 float2
  float2* Xs = (float2*)(sbuf + 272);    // 65 float2
  float* red = sbuf + 512;               // 1024 floats
  if (tid < 128)
    Gs[(tid >> 5) * 33 + (tid & 31)] =
        ((const float2*)(ws + OFF_G + (b * 128 + f1) * 256))[tid];
  __syncthreads();
  // phase A: X[f1+128 f2] = sum_t1 G'[t1] W128^{f2 t1} (quarters + shfl)
  {
    int lane = tid & 63, w = tid >> 6;
    int q = lane >> 4, f2l = lane & 15;
    int f2 = w * 16 + f2l;
    int r = (f2 * q) & 3;                // start angle f2*q/4 rev: exact
    float c = (r == 0) ? 1.f : (r == 2) ? -1.f : 0.f;
    float s = (r == 1) ? 1.f : (r == 3) ? -1.f : 0.f;
    float s1 = sin_rev((float)f2 * REV_128), c1 = cos_rev((float)f2 * REV_128);
    float xr = 0.f, xi = 0.f;
    const float2* g = Gs + q * 33;
    #pragma unroll 8
    for (int k = 0; k < 32; ++k) {
      float2 gv = g[k];
      xr = fmaf(gv.x, c, xr); xr = fmaf(gv.y, s, xr);
      xi = fmaf(gv.y, c, xi); xi = fmaf(-gv.x, s, xi);
      float cn = c * c1 - s * s1; s = s * c1 + c * s1; c = cn;
    }
    xr += __shfl_xor(xr, 16, 64); xi += __shfl_xor(xi, 16, 64);
    xr += __shfl_xor(xr, 32, 64); xi += __shfl_xor(xi, 32, 64);
    if (lane < 16) Xs[f2] = make_float2(xr, xi);
    if (f1 == 0 && tid < 32) {           // f2=64 (f=8192): W = (-1)^t1
      float er = 0.f, ei = 0.f;
      #pragma unroll
      for (int j = 0; j < 4; ++j) {
        int t1v = tid * 4 + j;
        float2 gv = Gs[(t1v >> 5) * 33 + (t1v & 31)];
        float sg = (j & 1) ? -1.f : 1.f;
        er = fmaf(gv.x, sg, er); ei = fmaf(gv.y, sg, ei);
      }
      #pragma unroll
      for (int off = 1; off <= 16; off <<= 1) {
        er += __shfl_xor(er, off, 64);
        ei += __shfl_xor(ei, off, 64);
      }
      if (tid == 0) Xs[64] = make_float2(er, ei);
    }
  }
  __syncthreads();
  // phase B: GC chain + CS-weighted reduction
  int e = tid & 127, fh = tid >> 7;
  float se  = emb[e] * (1.0f / 128.0f);  // ortho forward scale
  float d00 = w0[e * 129], d01 = w0[E * E + e * 129];
  float c00 = b0[e],       c01 = b0[E + e];
  float d10 = w1[e * 129], d11 = w1[E * E + e * 129];
  float c10 = b1[e],       c11 = b1[E + e];
  float d20 = w2[e * 129], d21 = w2[E * E + e * 129];
  float c20 = b2[e],       c21 = b2[E + e];
  float acc[EMB];
  #pragma unroll
  for (int m = 0; m < EMB; ++m) acc[m] = 0.f;
  const float* csbase = ws + OFF_CS + f1 * 16;

  for (int i = fh; i < nf2; i += 2) {
    int iu = __builtin_amdgcn_readfirstlane(i);
    const float* cs = csbase + (iu << 11);           // (f1 + 128*i)*16
    float2 X = Xs[i];
    float xr = X.x * se, xi = X.y * se;
    float or0 = fmaxf(fmaf(xr, d00, fmaf(-xi, d01, c00)), 0.f);
    float oi0 = fmaxf(fmaf(xi, d00, fmaf(xr, d01, c01)), 0.f);
    float pr = fmaxf(or0 - LAMBDA, 0.f), pi = fmaxf(oi0 - LAMBDA, 0.f);
    float or1 = fmaxf(fmaf(or0, d10, fmaf(-oi0, d11, c10)), 0.f);
    float oi1 = fmaxf(fmaf(oi0, d10, fmaf(or1, d11, c11)), 0.f);
    pr += fmaxf(or1 - LAMBDA, 0.f); pi += fmaxf(oi1 - LAMBDA, 0.f);
    float u2r = fmaf(or1, d20, fmaf(-oi1, d21, c20));
    float or2 = fmaxf(u2r, 0.f);
    float u2i = fmaf(oi1, d20, fmaf(or2, d21, c21));
    float zr = fmaxf(u2r - LAMBDA, 0.f) + pr;        // shrink(relu(u)) = max(u-l,0)
    float zi = fmaxf(u2i - LAMBDA, 0.f) + pi;
    #pragma unroll
    for (int m = 0; m < EMB; ++m)
      acc[m] = fmaf(zr, cs[m], fmaf(-zi, cs[8 + m], acc[m]));
  }
  __syncthreads();
  if (fh == 1) {
    #pragma unroll
    for (int m = 0; m < EMB; ++m) red[e * EMB + m] = acc[m];
  }
  __syncthreads();
  if (fh == 0) {
    float* P = ws + OFF_P + u * (E * EMB) + e * EMB;
    #pragma unroll
    for (int m = 0; m < EMB; ++m) P[m] = acc[m] + red[e * EMB + m];
  }
  // ----- finisher: last block of this b runs the FC head -----
  __syncthreads();                       // all P stores issued block-wide
  unsigned* ctr = (unsigned*)(ws + OFF_CTR);
  unsigned* flag = (unsigned*)sbuf;      // dedicated slot, no aliasing
  if (tid == 0) {
    __threadfence();                     // release P to device scope
    unsigned old = __hip_atomic_fetch_add(&ctr[b], 1u, __ATOMIC_ACQ_REL,
                                          __HIP_MEMORY_SCOPE_AGENT);
    flag[FLAG_SLOT] = (old == 127u) ? 1u : 0u;
  }
  __syncthreads();
  if (flag[FLAG_SLOT]) {
    __threadfence();                     // order subsequent loads (acquire)
    stage_fc(b, tid, x, emb, emb10, fc1w, fc1b, fc2w, fc2b, fc3w, fc3b,
             ws, out, sbuf);
  }
}

extern "C" void kernel_launch(void* const* d_in, const int* in_sizes, int n_in,
                              void* d_out, int out_size, void* d_ws, size_t ws_size,
                              hipStream_t stream) {
  const float* x     = (const float*)d_in[0];
  const float* emb   = (const float*)d_in[1];
  const float* w0    = (const float*)d_in[2];
  const float* b0    = (const float*)d_in[3];
  const float* w1    = (const float*)d_in[4];
  const float* b1    = (const float*)d_in[5];
  const float* w2    = (const float*)d_in[6];
  const float* b2    = (const float*)d_in[7];
  const float* emb10 = (const float*)d_in[8];
  const float* fc1w  = (const float*)d_in[9];
  const float* fc1b  = (const float*)d_in[10];
  const float* fc2w  = (const float*)d_in[11];
  const float* fc2b  = (const float*)d_in[12];
  const float* fc3w  = (const float*)d_in[13];
  const float* fc3b  = (const float*)d_in[14];
  float* ws  = (float*)d_ws;
  float* out = (float*)d_out;

  hipMemsetAsync(ws + OFF_CTR, 0, 16 * sizeof(unsigned), stream);
  k_prep<<<dim3(1024), 256, 0, stream>>>(x, emb10, ws);
  k_gcf<<<dim3(2048), 256, 0, stream>>>(x, emb, w0, b0, w1, b1, w2, b2, emb10,
                                        fc1w, fc1b, fc2w, fc2b, fc3w, fc3b,
                                        ws, out);
}

// Round 10
// 177.079 us; speedup vs baseline: 3.7786x; 1.7055x over previous
//
#include <hip/hip_runtime.h>
#include <math.h>

// Problem constants
#define Bsz   16
#define Lseq  512
#define Nfeat 32
#define E     128
#define EMB   8
#define FCH   64
#define Hd    256
#define PRE   96
#define M     16384   // N*L
#define MH    8193
#define LAMBDA 0.01f

// workspace layout (float offsets)
#define OFF_G   0          // 16*128*128*2 = 524288 floats
#define OFF_CS  524288     // 8193*16 -> 131088 floats
#define OFF_P   655376     // P[f1g][b][k]: 32*16*1024 = 524288 floats
// total = 1179664 floats = 4.7 MB

#define REV_M   6.103515625e-5f    // 1/16384 (angle in revolutions)
#define REV_128 7.8125e-3f         // 1/128

__device__ __forceinline__ float sin_rev(float r) { return __builtin_amdgcn_sinf(r); }
__device__ __forceinline__ float cos_rev(float r) { return __builtin_amdgcn_cosf(r); }

// ---------------- kernel 1: FFT pass1 + C/S tables ----------------
__global__ __launch_bounds__(256, 4)
void k_prep(const float* __restrict__ x, const float* __restrict__ emb10,
            float* __restrict__ ws) {
  __shared__ __align__(16) float sbuf[4160];
  int bid = blockIdx.x, tid = threadIdx.x;
  // ----- FFT pass 1: G'[b,f1,t1], unit = bid (16 b x 64 t1-pairs)
  {
    int b = bid >> 6, t1base = (bid & 63) << 1;
    int t1loc = tid >> 7, idx = tid & 127;
    {
      int t = (t1base + t1loc) + 128 * idx;
      int n = t >> 9, l = t & 511;
      sbuf[t1loc * 128 + idx] = x[b * (Lseq * Nfeat) + l * Nfeat + n];
    }
    __syncthreads();
    int f1 = idx, t1 = t1base + t1loc;
    float s1 = sin_rev((float)f1 * REV_128), c1 = cos_rev((float)f1 * REV_128);
    float c2 = c1 * c1 - s1 * s1, s2 = 2.f * s1 * c1;
    float cA = 1.f, sA = 0.f, cB = c1, sB = s1;
    float grA = 0.f, giA = 0.f, grB = 0.f, giB = 0.f;
    const float2* xc2 = (const float2*)(sbuf + t1loc * 128);
    #pragma unroll 8
    for (int h = 0; h < 64; ++h) {
      float2 xv = xc2[h];
      grA = fmaf(xv.x, cA, grA); giA = fmaf(xv.x, -sA, giA);
      grB = fmaf(xv.y, cB, grB); giB = fmaf(xv.y, -sB, giB);
      float cn = cA * c2 - sA * s2; sA = sA * c2 + cA * s2; cA = cn;
      cn = cB * c2 - sB * s2;       sB = sB * c2 + cB * s2; cB = cn;
    }
    float gr = grA + grB, gi = giA + giB;
    float rv = (float)(f1 * t1) * REV_M;            // f1*t1 < 16384
    float sb = sin_rev(rv), cb = cos_rev(rv);
    float grr = gr * cb + gi * sb;
    float gii = gi * cb - gr * sb;
    float* G = ws + OFF_G + ((b * 128 + f1) * 128 + t1) * 2;
    G[0] = grr; G[1] = gii;
  }
  __syncthreads();
  // ----- C/S tables: f = bid*8 + (tid>>5); emb10 staged TRANSPOSED e10T[m][t]
  {
    for (int j = tid; j < Lseq * EMB; j += 256) {
      int t = j >> 3, m = j & 7;
      sbuf[m * 512 + t] = emb10[j];     // coalesced global read
    }
    __syncthreads();
    int floc = tid >> 5, tl = tid & 31;
    int f = bid * 8 + floc;
    float ca[EMB], sa[EMB];
    #pragma unroll
    for (int m = 0; m < EMB; ++m) { ca[m] = 0.f; sa[m] = 0.f; }
    #pragma unroll 4
    for (int it = 0; it < 16; ++it) {
      int t = tl + 32 * it;
      int k = (f * t) & (M - 1);
      float rv = (float)k * REV_M;
      float cc = cos_rev(rv), ss = sin_rev(rv);
      #pragma unroll
      for (int m = 0; m < EMB; ++m) {
        float ev = sbuf[m * 512 + t];   // bank = t%32 = tl -> conflict-free
        ca[m] = fmaf(cc, ev, ca[m]);
        sa[m] = fmaf(ss, ev, sa[m]);
      }
    }
    #pragma unroll
    for (int off = 16; off >= 1; off >>= 1) {
      #pragma unroll
      for (int m = 0; m < EMB; ++m) {
        ca[m] += __shfl_xor(ca[m], off, 64);
        sa[m] += __shfl_xor(sa[m], off, 64);
      }
    }
    if (tl == 0) {
      float wf = (f == 0) ? (1.0f / 128.0f) : (2.0f / 128.0f);
      float* o = ws + OFF_CS + f * 16;
      #pragma unroll
      for (int m = 0; m < EMB; ++m) { o[m] = ca[m] * wf; o[8 + m] = sa[m] * wf; }
    }
    if (bid == 0 && tid < 64) {          // f = 8192: cos = (-1)^t, sin = 0
      int m = tid & 7, g = tid >> 3;
      float p = 0.f;
      #pragma unroll 8
      for (int j = 0; j < 64; ++j) p += sbuf[m * 512 + g + 8 * j];
      p = (g & 1) ? -p : p;
      p += __shfl_xor(p, 8, 64);
      p += __shfl_xor(p, 16, 64);
      p += __shfl_xor(p, 32, 64);
      if (g == 0) {
        ws[OFF_CS + 8192 * 16 + m] = p * (1.0f / 128.0f);
        ws[OFF_CS + 8192 * 16 + 8 + m] = 0.f;
      }
    }
  }
}

// ---------------- kernel 2: FFT pass2 + fourierGC + partial reduce (4 f1/block) ----------------
__global__ __launch_bounds__(256, 4)
void k_gcf(const float* __restrict__ emb,
           const float* __restrict__ w0, const float* __restrict__ b0,
           const float* __restrict__ w1, const float* __restrict__ b1,
           const float* __restrict__ w2, const float* __restrict__ b2,
           float* __restrict__ ws) {
  __shared__ __align__(16) float2 Gs[4][128];   // 4 KB
  __shared__ __align__(16) float2 Xs[257];      // ~2 KB
  __shared__ float red[E * EMB];                // 4 KB
  int f1g = blockIdx.x, b = blockIdx.y, tid = threadIdx.x;
  int f1base = f1g * 4;
  // load G[b, f1base..f1base+3, 0..127]: 512 float2, contiguous -> float4 x 256
  ((float4*)Gs)[tid] =
      ((const float4*)(ws + OFF_G + (b * 128 + f1base) * 256))[tid];
  __syncthreads();
  // phase A: thread (f1loc, f2) computes X[f1base+f1loc + 128*f2], 128-tap DFT
  {
    int f1loc = tid >> 6, f2 = tid & 63;
    float s1 = sin_rev((float)f2 * REV_128), c1 = cos_rev((float)f2 * REV_128);
    float c = 1.f, s = 0.f;
    float xr = 0.f, xi = 0.f;
    const float2* g = Gs[f1loc];
    #pragma unroll 8
    for (int t1 = 0; t1 < 128; ++t1) {
      float2 gv = g[t1];                 // wave-broadcast (same addr all lanes)
      xr = fmaf(gv.x, c, xr); xr = fmaf(gv.y, s, xr);
      xi = fmaf(gv.y, c, xi); xi = fmaf(-gv.x, s, xi);
      float cn = c * c1 - s * s1; s = s * c1 + c * s1; c = cn;
    }
    Xs[f1loc * 64 + f2] = make_float2(xr, xi);
    if (f1base == 0 && tid < 64) {       // f=8192: X = sum (-1)^t1 G[0][t1]
      float2 g0 = Gs[0][tid * 2], g1 = Gs[0][tid * 2 + 1];
      float er = g0.x - g1.x, ei = g0.y - g1.y;
      #pragma unroll
      for (int off = 1; off <= 32; off <<= 1) {
        er += __shfl_xor(er, off, 64);
        ei += __shfl_xor(ei, off, 64);
      }
      if (tid == 0) Xs[256] = make_float2(er, ei);
    }
  }
  __syncthreads();
  // phase B: GC chain + CS-weighted reduction over this block's 256(+1) f-values
  int e = tid & 127, fh = tid >> 7;
  int nf = (f1base == 0) ? 257 : 256;
  float se  = emb[e] * (1.0f / 128.0f);  // ortho forward scale
  float d00 = w0[e * 129], d01 = w0[E * E + e * 129];
  float c00 = b0[e],       c01 = b0[E + e];
  float d10 = w1[e * 129], d11 = w1[E * E + e * 129];
  float c10 = b1[e],       c11 = b1[E + e];
  float d20 = w2[e * 129], d21 = w2[E * E + e * 129];
  float c20 = b2[e],       c21 = b2[E + e];
  float acc[EMB];
  #pragma unroll
  for (int m = 0; m < EMB; ++m) acc[m] = 0.f;

  for (int i = fh; i < nf; i += 2) {
    int iu = __builtin_amdgcn_readfirstlane(i);      // wave-uniform -> SGPR
    int f = (iu == 256) ? 8192 : (f1base + (iu >> 6) + ((iu & 63) << 7));
    const float* cs = ws + OFF_CS + f * 16;          // scalar (s_load) path
    float2 X = Xs[iu];
    float xr = X.x * se, xi = X.y * se;
    float or0 = fmaxf(fmaf(xr, d00, fmaf(-xi, d01, c00)), 0.f);
    float oi0 = fmaxf(fmaf(xi, d00, fmaf(xr, d01, c01)), 0.f);
    float pr = fmaxf(or0 - LAMBDA, 0.f), pi = fmaxf(oi0 - LAMBDA, 0.f);
    float or1 = fmaxf(fmaf(or0, d10, fmaf(-oi0, d11, c10)), 0.f);
    float oi1 = fmaxf(fmaf(oi0, d10, fmaf(or1, d11, c11)), 0.f);
    pr += fmaxf(or1 - LAMBDA, 0.f); pi += fmaxf(oi1 - LAMBDA, 0.f);
    float u2r = fmaf(or1, d20, fmaf(-oi1, d21, c20));
    float or2 = fmaxf(u2r, 0.f);
    float u2i = fmaf(oi1, d20, fmaf(or2, d21, c21));
    float zr = fmaxf(u2r - LAMBDA, 0.f) + pr;        // shrink(relu(u)) = max(u-l,0)
    float zi = fmaxf(u2i - LAMBDA, 0.f) + pi;
    #pragma unroll
    for (int m = 0; m < EMB; ++m)
      acc[m] = fmaf(zr, cs[m], fmaf(-zi, cs[8 + m], acc[m]));
  }
  __syncthreads();
  if (fh == 1) {
    #pragma unroll
    for (int m = 0; m < EMB; ++m) red[e * EMB + m] = acc[m];
  }
  __syncthreads();
  if (fh == 0) {
    float* P = ws + OFF_P + (f1g * 16 + b) * (E * EMB) + e * EMB;
    #pragma unroll
    for (int m = 0; m < EMB; ++m) P[m] = acc[m] + red[e * EMB + m];
  }
}

// ---------------- kernel 3: P-reduce (32 chunks) + bias skip + FC head ----------------
__global__ __launch_bounds__(1024)
void k_fc(const float* __restrict__ x, const float* __restrict__ emb,
          const float* __restrict__ emb10,
          const float* __restrict__ fc1w, const float* __restrict__ fc1b,
          const float* __restrict__ fc2w, const float* __restrict__ fc2b,
          const float* __restrict__ fc3w, const float* __restrict__ fc3b,
          const float* __restrict__ ws, float* __restrict__ out) {
  int b = blockIdx.x;                   // grid 16
  __shared__ float h0s[E * EMB];
  __shared__ float h1s[FCH];
  __shared__ float h2s[Hd];
  __shared__ float hxs[EMB];
  __shared__ float scratch[1024];
  int tid = threadIdx.x;
  int lane = tid & 63, w = tid >> 6;    // 16 waves
  {
    int m = tid & 7, g = tid >> 3;      // 128 groups x 8 m
    float p = 0.f;
    #pragma unroll
    for (int l = g; l < Lseq; l += 128)
      p = fmaf(x[b * (Lseq * Nfeat) + l * Nfeat], emb10[l * EMB + m], p);
    scratch[tid] = p;
  }
  // P-reduce: thread owns k = tid, 32 chunks of stride 16*1024
  const float* P = ws + OFF_P + b * (E * EMB) + tid;
  float a = 0.f;
  #pragma unroll
  for (int c = 0; c < 32; ++c) a += P[c * (Bsz * E * EMB)];
  __syncthreads();
  if (tid < 8) {
    float s = 0.f;
    #pragma unroll 16
    for (int g = 0; g < 128; ++g) s += scratch[g * 8 + tid];
    hxs[tid] = s;
  }
  __syncthreads();
  h0s[tid] = a + emb[tid >> 3] * hxs[tid & 7];
  __syncthreads();
  // fc1: 64 outputs, K=1024; wave-per-output (coalesced weights)
  #pragma unroll
  for (int oo = 0; oo < 4; ++oo) {
    int o = oo * 16 + w;
    const float* wr = fc1w + o * (E * EMB);
    float acc = 0.f;
    #pragma unroll
    for (int j = 0; j < 16; ++j) acc = fmaf(h0s[lane + 64 * j], wr[lane + 64 * j], acc);
    #pragma unroll
    for (int off = 32; off >= 1; off >>= 1) acc += __shfl_xor(acc, off, 64);
    if (lane == 0) { float v = acc + fc1b[o]; h1s[o] = v > 0.f ? v : 0.01f * v; }
  }
  __syncthreads();
  // fc2: 256 outputs, K=64
  #pragma unroll
  for (int oo = 0; oo < 16; ++oo) {
    int o = oo * 16 + w;
    float acc = h1s[lane] * fc2w[o * FCH + lane];
    #pragma unroll
    for (int off = 32; off >= 1; off >>= 1) acc += __shfl_xor(acc, off, 64);
    if (lane == 0) { float v = acc + fc2b[o]; h2s[o] = v > 0.f ? v : 0.01f * v; }
  }
  __syncthreads();
  // fc3: 96 outputs, K=256
  #pragma unroll
  for (int oo = 0; oo < 6; ++oo) {
    int o = oo * 16 + w;
    const float* wr = fc3w + o * Hd;
    float acc = 0.f;
    #pragma unroll
    for (int j = 0; j < 4; ++j) acc = fmaf(h2s[lane + 64 * j], wr[lane + 64 * j], acc);
    #pragma unroll
    for (int off = 32; off >= 1; off >>= 1) acc += __shfl_xor(acc, off, 64);
    if (lane == 0) out[b * PRE + o] = acc + fc3b[o];
  }
}

extern "C" void kernel_launch(void* const* d_in, const int* in_sizes, int n_in,
                              void* d_out, int out_size, void* d_ws, size_t ws_size,
                              hipStream_t stream) {
  const float* x     = (const float*)d_in[0];
  const float* emb   = (const float*)d_in[1];
  const float* w0    = (const float*)d_in[2];
  const float* b0    = (const float*)d_in[3];
  const float* w1    = (const float*)d_in[4];
  const float* b1    = (const float*)d_in[5];
  const float* w2    = (const float*)d_in[6];
  const float* b2    = (const float*)d_in[7];
  const float* emb10 = (const float*)d_in[8];
  const float* fc1w  = (const float*)d_in[9];
  const float* fc1b  = (const float*)d_in[10];
  const float* fc2w  = (const float*)d_in[11];
  const float* fc2b  = (const float*)d_in[12];
  const float* fc3w  = (const float*)d_in[13];
  const float* fc3b  = (const float*)d_in[14];
  float* ws  = (float*)d_ws;
  float* out = (float*)d_out;

  k_prep<<<dim3(1024), 256, 0, stream>>>(x, emb10, ws);
  k_gcf<<<dim3(32, Bsz), 256, 0, stream>>>(emb, w0, b0, w1, b1, w2, b2, ws);
  k_fc<<<dim3(Bsz), 1024, 0, stream>>>(x, emb, emb10, fc1w, fc1b, fc2w, fc2b,
                                       fc3w, fc3b, ws, out);
}

// Round 11
// 148.383 us; speedup vs baseline: 4.5093x; 1.1934x over previous
//
#include <hip/hip_runtime.h>
#include <math.h>

// Problem constants
#define Bsz   16
#define Lseq  512
#define Nfeat 32
#define E     128
#define EMB   8
#define FCH   64
#define Hd    256
#define PRE   96
#define M     16384   // N*L
#define MH    8193
#define LAMBDA 0.01f

// workspace layout (float offsets)
#define OFF_G   0          // 16*128*128*2 = 524288 floats
#define OFF_CS  524288     // 8193*16 -> 131088 floats
#define OFF_P   655376     // P[f1g][b][k]: 32*16*1024 = 524288 floats
// total = 1179664 floats = 4.7 MB

#define REV_M   6.103515625e-5f    // 1/16384 (angle in revolutions)
#define REV_128 7.8125e-3f         // 1/128

__device__ __forceinline__ float sin_rev(float r) { return __builtin_amdgcn_sinf(r); }
__device__ __forceinline__ float cos_rev(float r) { return __builtin_amdgcn_cosf(r); }

// ---------------- kernel 1: FFT pass1 + C/S tables ----------------
__global__ __launch_bounds__(256, 4)
void k_prep(const float* __restrict__ x, const float* __restrict__ emb10,
            float* __restrict__ ws) {
  __shared__ __align__(16) float sbuf[4160];
  int bid = blockIdx.x, tid = threadIdx.x;
  // ----- FFT pass 1: G'[b,f1,t1], unit = bid (16 b x 64 t1-pairs)
  {
    int b = bid >> 6, t1base = (bid & 63) << 1;
    int t1loc = tid >> 7, idx = tid & 127;
    {
      int t = (t1base + t1loc) + 128 * idx;
      int n = t >> 9, l = t & 511;
      sbuf[t1loc * 128 + idx] = x[b * (Lseq * Nfeat) + l * Nfeat + n];
    }
    __syncthreads();
    int f1 = idx, t1 = t1base + t1loc;
    float s1 = sin_rev((float)f1 * REV_128), c1 = cos_rev((float)f1 * REV_128);
    float c2 = c1 * c1 - s1 * s1, s2 = 2.f * s1 * c1;
    float cA = 1.f, sA = 0.f, cB = c1, sB = s1;
    float grA = 0.f, giA = 0.f, grB = 0.f, giB = 0.f;
    const float2* xc2 = (const float2*)(sbuf + t1loc * 128);
    #pragma unroll 8
    for (int h = 0; h < 64; ++h) {
      float2 xv = xc2[h];
      grA = fmaf(xv.x, cA, grA); giA = fmaf(xv.x, -sA, giA);
      grB = fmaf(xv.y, cB, grB); giB = fmaf(xv.y, -sB, giB);
      float cn = cA * c2 - sA * s2; sA = sA * c2 + cA * s2; cA = cn;
      cn = cB * c2 - sB * s2;       sB = sB * c2 + cB * s2; cB = cn;
    }
    float gr = grA + grB, gi = giA + giB;
    float rv = (float)(f1 * t1) * REV_M;            // f1*t1 < 16384
    float sb = sin_rev(rv), cb = cos_rev(rv);
    float grr = gr * cb + gi * sb;
    float gii = gi * cb - gr * sb;
    float* G = ws + OFF_G + ((b * 128 + f1) * 128 + t1) * 2;
    G[0] = grr; G[1] = gii;
  }
  __syncthreads();
  // ----- C/S tables: f = bid*8 + (tid>>5); emb10 staged TRANSPOSED e10T[m][t]
  {
    for (int j = tid; j < Lseq * EMB; j += 256) {
      int t = j >> 3, m = j & 7;
      sbuf[m * 512 + t] = emb10[j];     // coalesced global read
    }
    __syncthreads();
    int floc = tid >> 5, tl = tid & 31;
    int f = bid * 8 + floc;
    float ca[EMB], sa[EMB];
    #pragma unroll
    for (int m = 0; m < EMB; ++m) { ca[m] = 0.f; sa[m] = 0.f; }
    #pragma unroll 4
    for (int it = 0; it < 16; ++it) {
      int t = tl + 32 * it;
      int k = (f * t) & (M - 1);
      float rv = (float)k * REV_M;
      float cc = cos_rev(rv), ss = sin_rev(rv);
      #pragma unroll
      for (int m = 0; m < EMB; ++m) {
        float ev = sbuf[m * 512 + t];   // bank = t%32 = tl -> conflict-free
        ca[m] = fmaf(cc, ev, ca[m]);
        sa[m] = fmaf(ss, ev, sa[m]);
      }
    }
    #pragma unroll
    for (int off = 16; off >= 1; off >>= 1) {
      #pragma unroll
      for (int m = 0; m < EMB; ++m) {
        ca[m] += __shfl_xor(ca[m], off, 64);
        sa[m] += __shfl_xor(sa[m], off, 64);
      }
    }
    if (tl == 0) {
      float wf = (f == 0) ? (1.0f / 128.0f) : (2.0f / 128.0f);
      float* o = ws + OFF_CS + f * 16;
      #pragma unroll
      for (int m = 0; m < EMB; ++m) { o[m] = ca[m] * wf; o[8 + m] = sa[m] * wf; }
    }
    if (bid == 0 && tid < 64) {          // f = 8192: cos = (-1)^t, sin = 0
      int m = tid & 7, g = tid >> 3;
      float p = 0.f;
      #pragma unroll 8
      for (int j = 0; j < 64; ++j) p += sbuf[m * 512 + g + 8 * j];
      p = (g & 1) ? -p : p;
      p += __shfl_xor(p, 8, 64);
      p += __shfl_xor(p, 16, 64);
      p += __shfl_xor(p, 32, 64);
      if (g == 0) {
        ws[OFF_CS + 8192 * 16 + m] = p * (1.0f / 128.0f);
        ws[OFF_CS + 8192 * 16 + 8 + m] = 0.f;
      }
    }
  }
}

// ---------------- kernel 2: FFT pass2 + fourierGC + partial reduce ----------------
// 1024 threads/block, 4 f1 per block, 512 blocks -> 32 waves/CU
__global__ __launch_bounds__(1024, 8)
void k_gcf(const float* __restrict__ emb,
           const float* __restrict__ w0, const float* __restrict__ b0,
           const float* __restrict__ w1, const float* __restrict__ b1,
           const float* __restrict__ w2, const float* __restrict__ b2,
           float* __restrict__ ws) {
  __shared__ __align__(16) float2 Gs[4 * 132];  // quarter-skewed (stride 33)
  __shared__ __align__(16) float2 Xs[257];
  __shared__ float red[7 * 1024];               // 28 KB fh-partials
  int f1g = blockIdx.x, b = blockIdx.y, tid = threadIdx.x;
  int f1base = f1g * 4;
  if (tid < 512) {
    float2 v = ((const float2*)(ws + OFF_G + (b * 128 + f1base) * 256))[tid];
    int f1loc = tid >> 7, t1 = tid & 127;
    Gs[f1loc * 132 + (t1 >> 5) * 33 + (t1 & 31)] = v;
  }
  __syncthreads();
  // phase A: thread (f1loc, f2, q) computes 32-tap quarter; shfl-reduce quarters
  {
    int w = tid >> 6, lane = tid & 63;
    int f1loc = w >> 2;
    int q = lane >> 4, f2 = ((w & 3) << 4) + (lane & 15);
    int r = (f2 * q) & 3;                // start angle f2*q/4 rev: exact
    float c = (r == 0) ? 1.f : (r == 2) ? -1.f : 0.f;
    float s = (r == 1) ? 1.f : (r == 3) ? -1.f : 0.f;
    float s1 = sin_rev((float)f2 * REV_128), c1 = cos_rev((float)f2 * REV_128);
    float xr = 0.f, xi = 0.f;
    const float2* g = Gs + f1loc * 132 + q * 33;
    #pragma unroll 8
    for (int k = 0; k < 32; ++k) {
      float2 gv = g[k];
      xr = fmaf(gv.x, c, xr); xr = fmaf(gv.y, s, xr);
      xi = fmaf(gv.y, c, xi); xi = fmaf(-gv.x, s, xi);
      float cn = c * c1 - s * s1; s = s * c1 + c * s1; c = cn;
    }
    xr += __shfl_xor(xr, 16, 64); xi += __shfl_xor(xi, 16, 64);
    xr += __shfl_xor(xr, 32, 64); xi += __shfl_xor(xi, 32, 64);
    if (lane < 16) Xs[f1loc * 64 + f2] = make_float2(xr, xi);
    if (f1base == 0 && tid < 64) {       // f=8192: X = sum (-1)^t1 G[0][t1]
      int t1v = tid * 2;
      const float2* g0p = Gs + (t1v >> 5) * 33;
      float2 g0 = g0p[t1v & 31], g1 = g0p[(t1v & 31) + 1];
      float er = g0.x - g1.x, ei = g0.y - g1.y;
      #pragma unroll
      for (int off = 1; off <= 32; off <<= 1) {
        er += __shfl_xor(er, off, 64);
        ei += __shfl_xor(ei, off, 64);
      }
      if (tid == 0) Xs[256] = make_float2(er, ei);
    }
  }
  __syncthreads();
  // phase B: GC chain + CS-weighted reduce; f split 8 ways (fh = tid>>7)
  int e = tid & 127, fh = tid >> 7;      // fh in [0,8)
  int nf = (f1base == 0) ? 257 : 256;
  float se  = emb[e] * (1.0f / 128.0f);  // ortho forward scale
  float d00 = w0[e * 129], d01 = w0[E * E + e * 129];
  float c00 = b0[e],       c01 = b0[E + e];
  float d10 = w1[e * 129], d11 = w1[E * E + e * 129];
  float c10 = b1[e],       c11 = b1[E + e];
  float d20 = w2[e * 129], d21 = w2[E * E + e * 129];
  float c20 = b2[e],       c21 = b2[E + e];
  float acc[EMB];
  #pragma unroll
  for (int m = 0; m < EMB; ++m) acc[m] = 0.f;

  for (int i = fh; i < nf; i += 8) {
    int iu = __builtin_amdgcn_readfirstlane(i);      // wave-uniform -> SGPR
    int f = (iu == 256) ? 8192 : (f1base + (iu >> 6) + ((iu & 63) << 7));
    const float* cs = ws + OFF_CS + f * 16;          // scalar (s_load) path
    float2 X = Xs[iu];
    float xr = X.x * se, xi = X.y * se;
    float or0 = fmaxf(fmaf(xr, d00, fmaf(-xi, d01, c00)), 0.f);
    float oi0 = fmaxf(fmaf(xi, d00, fmaf(xr, d01, c01)), 0.f);
    float pr = fmaxf(or0 - LAMBDA, 0.f), pi = fmaxf(oi0 - LAMBDA, 0.f);
    float or1 = fmaxf(fmaf(or0, d10, fmaf(-oi0, d11, c10)), 0.f);
    float oi1 = fmaxf(fmaf(oi0, d10, fmaf(or1, d11, c11)), 0.f);
    pr += fmaxf(or1 - LAMBDA, 0.f); pi += fmaxf(oi1 - LAMBDA, 0.f);
    float u2r = fmaf(or1, d20, fmaf(-oi1, d21, c20));
    float or2 = fmaxf(u2r, 0.f);
    float u2i = fmaf(oi1, d20, fmaf(or2, d21, c21));
    float zr = fmaxf(u2r - LAMBDA, 0.f) + pr;        // shrink(relu(u)) = max(u-l,0)
    float zi = fmaxf(u2i - LAMBDA, 0.f) + pi;
    #pragma unroll
    for (int m = 0; m < EMB; ++m)
      acc[m] = fmaf(zr, cs[m], fmaf(-zi, cs[8 + m], acc[m]));
  }
  __syncthreads();
  if (fh > 0) {
    #pragma unroll
    for (int m = 0; m < EMB; ++m) red[(fh - 1) * 1024 + e * EMB + m] = acc[m];
  }
  __syncthreads();
  if (fh == 0) {
    #pragma unroll
    for (int j = 0; j < 7; ++j)
      #pragma unroll
      for (int m = 0; m < EMB; ++m) acc[m] += red[j * 1024 + e * EMB + m];
    float* P = ws + OFF_P + (f1g * 16 + b) * (E * EMB) + e * EMB;
    #pragma unroll
    for (int m = 0; m < EMB; ++m) P[m] = acc[m];
  }
}

// ---------------- kernel 3: P-reduce (32 chunks) + bias skip + FC head ----------------
__global__ __launch_bounds__(1024)
void k_fc(const float* __restrict__ x, const float* __restrict__ emb,
          const float* __restrict__ emb10,
          const float* __restrict__ fc1w, const float* __restrict__ fc1b,
          const float* __restrict__ fc2w, const float* __restrict__ fc2b,
          const float* __restrict__ fc3w, const float* __restrict__ fc3b,
          const float* __restrict__ ws, float* __restrict__ out) {
  int b = blockIdx.x;                   // grid 16
  __shared__ float h0s[E * EMB];
  __shared__ float h1s[FCH];
  __shared__ float h2s[Hd];
  __shared__ float hxs[EMB];
  __shared__ float scratch[1024];
  int tid = threadIdx.x;
  int lane = tid & 63, w = tid >> 6;    // 16 waves
  {
    int m = tid & 7, g = tid >> 3;      // 128 groups x 8 m
    float p = 0.f;
    #pragma unroll
    for (int l = g; l < Lseq; l += 128)
      p = fmaf(x[b * (Lseq * Nfeat) + l * Nfeat], emb10[l * EMB + m], p);
    scratch[tid] = p;
  }
  // P-reduce: thread owns k = tid, 32 chunks of stride 16*1024
  const float* P = ws + OFF_P + b * (E * EMB) + tid;
  float a = 0.f;
  #pragma unroll
  for (int c = 0; c < 32; ++c) a += P[c * (Bsz * E * EMB)];
  __syncthreads();
  if (tid < 8) {
    float s = 0.f;
    #pragma unroll 16
    for (int g = 0; g < 128; ++g) s += scratch[g * 8 + tid];
    hxs[tid] = s;
  }
  __syncthreads();
  h0s[tid] = a + emb[tid >> 3] * hxs[tid & 7];
  __syncthreads();
  // fc1: 64 outputs, K=1024; wave-per-output (coalesced weights)
  #pragma unroll
  for (int oo = 0; oo < 4; ++oo) {
    int o = oo * 16 + w;
    const float* wr = fc1w + o * (E * EMB);
    float acc = 0.f;
    #pragma unroll
    for (int j = 0; j < 16; ++j) acc = fmaf(h0s[lane + 64 * j], wr[lane + 64 * j], acc);
    #pragma unroll
    for (int off = 32; off >= 1; off >>= 1) acc += __shfl_xor(acc, off, 64);
    if (lane == 0) { float v = acc + fc1b[o]; h1s[o] = v > 0.f ? v : 0.01f * v; }
  }
  __syncthreads();
  // fc2: 256 outputs, K=64
  #pragma unroll
  for (int oo = 0; oo < 16; ++oo) {
    int o = oo * 16 + w;
    float acc = h1s[lane] * fc2w[o * FCH + lane];
    #pragma unroll
    for (int off = 32; off >= 1; off >>= 1) acc += __shfl_xor(acc, off, 64);
    if (lane == 0) { float v = acc + fc2b[o]; h2s[o] = v > 0.f ? v : 0.01f * v; }
  }
  __syncthreads();
  // fc3: 96 outputs, K=256
  #pragma unroll
  for (int oo = 0; oo < 6; ++oo) {
    int o = oo * 16 + w;
    const float* wr = fc3w + o * Hd;
    float acc = 0.f;
    #pragma unroll
    for (int j = 0; j < 4; ++j) acc = fmaf(h2s[lane + 64 * j], wr[lane + 64 * j], acc);
    #pragma unroll
    for (int off = 32; off >= 1; off >>= 1) acc += __shfl_xor(acc, off, 64);
    if (lane == 0) out[b * PRE + o] = acc + fc3b[o];
  }
}

extern "C" void kernel_launch(void* const* d_in, const int* in_sizes, int n_in,
                              void* d_out, int out_size, void* d_ws, size_t ws_size,
                              hipStream_t stream) {
  const float* x     = (const float*)d_in[0];
  const float* emb   = (const float*)d_in[1];
  const float* w0    = (const float*)d_in[2];
  const float* b0    = (const float*)d_in[3];
  const float* w1    = (const float*)d_in[4];
  const float* b1    = (const float*)d_in[5];
  const float* w2    = (const float*)d_in[6];
  const float* b2    = (const float*)d_in[7];
  const float* emb10 = (const float*)d_in[8];
  const float* fc1w  = (const float*)d_in[9];
  const float* fc1b  = (const float*)d_in[10];
  const float* fc2w  = (const float*)d_in[11];
  const float* fc2b  = (const float*)d_in[12];
  const float* fc3w  = (const float*)d_in[13];
  const float* fc3b  = (const float*)d_in[14];
  float* ws  = (float*)d_ws;
  float* out = (float*)d_out;

  k_prep<<<dim3(1024), 256, 0, stream>>>(x, emb10, ws);
  k_gcf<<<dim3(32, Bsz), 1024, 0, stream>>>(emb, w0, b0, w1, b1, w2, b2, ws);
  k_fc<<<dim3(Bsz), 1024, 0, stream>>>(x, emb, emb10, fc1w, fc1b, fc2w, fc2b,
                                       fc3w, fc3b, ws, out);
}